// Round 6
// baseline (92.594 us; speedup 1.0000x reference)
//
#include <hip/hip_runtime.h>
#include <hip/hip_bf16.h>

#define CSTF 1.676543f
#define TSTRIDE 68   // LDS table row stride in floats (16B-aligned, bank-spreading)

typedef __bf16 bf16x8 __attribute__((ext_vector_type(8)));
typedef float  f32x4  __attribute__((ext_vector_type(4)));

__device__ __forceinline__ float silu_n(float y) {
    return CSTF * y * __builtin_amdgcn_rcpf(1.0f + __expf(-y));
}

struct XG { f32x4 a, b, c, d; };

__device__ __forceinline__ XG loadx(const float* p) {
    XG r;
    r.a = *(const f32x4*)(p);
    r.b = *(const f32x4*)(p + 4);
    r.c = *(const f32x4*)(p + 32);
    r.d = *(const f32x4*)(p + 36);
    return r;
}

// One 16-atom group. cur = x fragments, vb = this lane's 4 batch indices
// (atoms gi*16 + 4g + 0..3). Accumulates into the block-shared LDS table.
#define PROC16(cur, vb) { \
  bf16x8 a0, a1; \
  _Pragma("unroll") \
  for (int j = 0; j < 4; ++j) { \
    a0[j] = (__bf16)cur.a[j]; a0[j+4] = (__bf16)cur.b[j]; \
    a1[j] = (__bf16)cur.c[j]; a1[j+4] = (__bf16)cur.d[j]; \
  } \
  const f32x4 zf = {0.f, 0.f, 0.f, 0.f}; \
  _Pragma("unroll") \
  for (int nt = 0; nt < 4; ++nt) { \
    f32x4 acc = __builtin_amdgcn_mfma_f32_16x16x32_bf16(a0, wf0[0][nt], zf, 0, 0, 0); \
    acc = __builtin_amdgcn_mfma_f32_16x16x32_bf16(a1, wf0[1][nt], acc, 0, 0, 0); \
    _Pragma("unroll") \
    for (int r = 0; r < 4; ++r) \
      sbuf[w][4*g + r][nt*16 + c] = __float2bfloat16(silu_n(acc[r])); \
  } \
  const bf16x8 sa0 = *(const bf16x8*)&sbuf[w][c][g*8]; \
  const bf16x8 sa1 = *(const bf16x8*)&sbuf[w][c][g*8 + 32]; \
  _Pragma("unroll") \
  for (int nt = 0; nt < 4; ++nt) { \
    f32x4 z = __builtin_amdgcn_mfma_f32_16x16x32_bf16(sa0, wf1[0][nt], zf, 0, 0, 0); \
    z = __builtin_amdgcn_mfma_f32_16x16x32_bf16(sa1, wf1[1][nt], z, 0, 0, 0); \
    atomicAdd(&table[vb.x * TSTRIDE + nt*16 + c], silu_n(z[0])); \
    atomicAdd(&table[vb.y * TSTRIDE + nt*16 + c], silu_n(z[1])); \
    atomicAdd(&table[vb.z * TSTRIDE + nt*16 + c], silu_n(z[2])); \
    atomicAdd(&table[vb.w * TSTRIDE + nt*16 + c], silu_n(z[3])); \
  } \
}

// Phase 1: s2 = silu(silu(x@W0*.125)@W1*.125) via bf16 MFMA; per-block LDS
// batch table (ds_add, zero global atomics); flush = plain coalesced stores
// to a per-block ws slice. 256 blocks x 8 waves x 64 atoms.
__global__ __launch_bounds__(512, 1) void phase1(
    const float* __restrict__ x, const int* __restrict__ bidx,
    const float* __restrict__ W0, const float* __restrict__ W1,
    float* __restrict__ ws)
{
    __shared__ float table[512 * TSTRIDE];                    // 139,264 B
    __shared__ __align__(16) __hip_bfloat16 sbuf[8][16][72];  //  18,432 B
    const int tid  = threadIdx.x;
    const int lane = tid & 63;
    const int w    = tid >> 6;
    const int c    = lane & 15;
    const int g    = lane >> 4;

    const int wbase = (blockIdx.x * 8 + w) * 64;   // 64 atoms per wave
    const float* px = x + (size_t)(wbase + c) * 1024 + g * 8;

    // issue first group's loads before anything else
    XG   cc = loadx(px);
    int4 bb = *(const int4*)&bidx[wbase + 4 * g];

    // zero the LDS table
    for (int i = tid; i < 512 * TSTRIDE; i += 512) table[i] = 0.0f;

    // Preload W0/W1 as B-fragments, 1/sqrt(64) folded in (L2/L3-hot).
    bf16x8 wf0[2][4], wf1[2][4];
#pragma unroll
    for (int ks = 0; ks < 2; ++ks)
#pragma unroll
        for (int nt = 0; nt < 4; ++nt) {
            bf16x8 f0, f1;
#pragma unroll
            for (int j = 0; j < 8; ++j) {
                const int k = ks * 32 + g * 8 + j;
                f0[j] = (__bf16)(0.125f * W0[k * 256 + nt * 16 + c]);
                f1[j] = (__bf16)(0.125f * W1[k * 256 + nt * 16 + c]);
            }
            wf0[ks][nt] = f0;
            wf1[ks][nt] = f1;
        }
    __syncthreads();

#pragma unroll 1
    for (int gi = 0; gi < 4; ++gi) {
        XG   nc = cc;
        int4 nb = bb;
        if (gi < 3) {   // prefetch next 16-atom group
            nc = loadx(px + (size_t)(gi + 1) * 16 * 1024);
            nb = *(const int4*)&bidx[wbase + (gi + 1) * 16 + 4 * g];
        }
        PROC16(cc, bb);
        cc = nc;
        bb = nb;
    }
    __syncthreads();

    // flush 512x64 table (strip the pad) to this block's ws slice
    float* dst = ws + (size_t)blockIdx.x * 32768;
    for (int j = tid; j < 8192; j += 512) {
        const int b  = j >> 4;
        const int o4 = (j & 15) * 4;
        *(f32x4*)&dst[b * 64 + o4] = *(const f32x4*)&table[b * TSTRIDE + o4];
    }
}

// out[b, t] = 0.125 * sum_o (sum_blk T[blk][b][o]) * Wout[o, t]
__global__ __launch_bounds__(128) void phase2(
    const float* __restrict__ ws, const float* __restrict__ Wout,
    float* __restrict__ out)
{
    __shared__ float sp[128];
    const int b = blockIdx.x, t = threadIdx.x;
    const int o = t & 63, half = t >> 6;

    float s = 0.f;
    for (int blk = half; blk < 256; blk += 2)
        s += ws[(size_t)blk * 32768 + b * 64 + o];
    sp[t] = s;
    __syncthreads();

    float acc = 0.f;
#pragma unroll
    for (int o2 = 0; o2 < 64; ++o2) {
        const float S = sp[o2] + sp[o2 + 64];
        acc = fmaf(S, Wout[o2 * 128 + t], acc);
    }
    out[b * 128 + t] = 0.125f * acc;
}

extern "C" void kernel_launch(void* const* d_in, const int* in_sizes, int n_in,
                              void* d_out, int out_size, void* d_ws, size_t ws_size,
                              hipStream_t stream)
{
    const float* x    = (const float*)d_in[0];
    const int*   bidx = (const int*)d_in[1];
    const float* W0   = (const float*)d_in[3];   // W0_0 (64,256)
    const float* W1   = (const float*)d_in[7];   // W1_0 (64,256)
    const float* Wout = (const float*)d_in[11];  // W_out (64,128)
    float* ws  = (float*)d_ws;                    // 256 block tables of 512x64
    float* out = (float*)d_out;

    hipLaunchKernelGGL(phase1, dim3(256), dim3(512), 0, stream, x, bidx, W0, W1, ws);
    hipLaunchKernelGGL(phase2, dim3(512), dim3(128), 0, stream, ws, Wout, out);
}

// Round 7
// 59.103 us; speedup vs baseline: 1.5667x; 1.5667x over previous
//
#include <hip/hip_runtime.h>
#include <hip/hip_bf16.h>

#define CSTF 1.676543f
#define NREP 64

typedef __bf16 bf16x8 __attribute__((ext_vector_type(8)));
typedef float  f32x4  __attribute__((ext_vector_type(4)));

__device__ __forceinline__ float silu_n(float y) {
    return CSTF * y * __builtin_amdgcn_rcpf(1.0f + __expf(-y));
}

struct XG { f32x4 a, b, c, d; };

__device__ __forceinline__ XG loadx(const float* p) {
    XG r;
    r.a = *(const f32x4*)(p);
    r.b = *(const f32x4*)(p + 4);
    r.c = *(const f32x4*)(p + 32);
    r.d = *(const f32x4*)(p + 36);
    return r;
}

// One 16-atom group; vb = this lane's 4 batch indices (atoms 4g+0..3 of group).
#define PROC16(cur, vb) { \
  bf16x8 a0, a1; \
  _Pragma("unroll") \
  for (int j = 0; j < 4; ++j) { \
    a0[j] = (__bf16)cur.a[j]; a0[j+4] = (__bf16)cur.b[j]; \
    a1[j] = (__bf16)cur.c[j]; a1[j+4] = (__bf16)cur.d[j]; \
  } \
  const f32x4 zf = {0.f, 0.f, 0.f, 0.f}; \
  _Pragma("unroll") \
  for (int nt = 0; nt < 4; ++nt) { \
    f32x4 acc = __builtin_amdgcn_mfma_f32_16x16x32_bf16(a0, wf0[0][nt], zf, 0, 0, 0); \
    acc = __builtin_amdgcn_mfma_f32_16x16x32_bf16(a1, wf0[1][nt], acc, 0, 0, 0); \
    _Pragma("unroll") \
    for (int r = 0; r < 4; ++r) \
      sb[w][4*g + r][nt*16 + c] = __float2bfloat16(silu_n(acc[r])); \
  } \
  const bf16x8 sa0 = *(const bf16x8*)&sb[w][c][g*8]; \
  const bf16x8 sa1 = *(const bf16x8*)&sb[w][c][g*8 + 32]; \
  _Pragma("unroll") \
  for (int nt = 0; nt < 4; ++nt) { \
    f32x4 z = __builtin_amdgcn_mfma_f32_16x16x32_bf16(sa0, wf1[0][nt], zf, 0, 0, 0); \
    z = __builtin_amdgcn_mfma_f32_16x16x32_bf16(sa1, wf1[1][nt], z, 0, 0, 0); \
    atomicAdd(&Srep[(vb.x << 6) + nt*16 + c], silu_n(z[0])); \
    atomicAdd(&Srep[(vb.y << 6) + nt*16 + c], silu_n(z[1])); \
    atomicAdd(&Srep[(vb.z << 6) + nt*16 + c], silu_n(z[2])); \
    atomicAdd(&Srep[(vb.w << 6) + nt*16 + c], silu_n(z[3])); \
  } \
}

// Phase 1: s2 = silu(silu(x@W0*.125)@W1*.125) via bf16 MFMA, atomics into
// NREP replicated S[512][64] tables. 512 blocks x 4 waves x 64 atoms.
__global__ __launch_bounds__(256, 3) void phase1(
    const float* __restrict__ x, const int* __restrict__ bidx,
    const float* __restrict__ W0, const float* __restrict__ W1,
    float* __restrict__ S)
{
    __shared__ __align__(16) __hip_bfloat16 sb[4][16][72];
    const int tid  = threadIdx.x;
    const int lane = tid & 63;
    const int w    = tid >> 6;
    const int c    = lane & 15;
    const int g    = lane >> 4;

    const int wbase = (blockIdx.x * 4 + w) * 64;   // 64 atoms per wave
    const float* px = x + (size_t)(wbase + c) * 1024 + g * 8;

    // first group's loads before the (L2-hot) weight preload
    XG   cc = loadx(px);
    int4 bb = *(const int4*)&bidx[wbase + 4 * g];

    // W0/W1 as B-fragments, 1/sqrt(64) folded into bf16 weights
    bf16x8 wf0[2][4], wf1[2][4];
#pragma unroll
    for (int ks = 0; ks < 2; ++ks)
#pragma unroll
        for (int nt = 0; nt < 4; ++nt) {
            bf16x8 f0, f1;
#pragma unroll
            for (int j = 0; j < 8; ++j) {
                const int k = ks * 32 + g * 8 + j;
                f0[j] = (__bf16)(0.125f * W0[k * 256 + nt * 16 + c]);
                f1[j] = (__bf16)(0.125f * W1[k * 256 + nt * 16 + c]);
            }
            wf0[ks][nt] = f0;
            wf1[ks][nt] = f1;
        }

    float* Srep = S + ((size_t)(blockIdx.x & (NREP - 1)) << 15);

#pragma unroll 1
    for (int gi = 0; gi < 4; ++gi) {
        XG   nc = cc;
        int4 nb = bb;
        if (gi < 3) {   // prefetch next 16-atom group
            nc = loadx(px + (size_t)(gi + 1) * 16 * 1024);
            nb = *(const int4*)&bidx[wbase + (gi + 1) * 16 + 4 * g];
        }
        PROC16(cc, bb);
        cc = nc;
        bb = nb;
    }
}

// out[b, t] = 0.125 * sum_o (sum_r S_r[b,o]) * Wout[o, t]
__global__ __launch_bounds__(128) void phase2(
    const float* __restrict__ S, const float* __restrict__ Wout,
    float* __restrict__ out)
{
    __shared__ float sp[64];
    const int b = blockIdx.x, t = threadIdx.x;
    if (t < 64) {
        float s = 0.f;
#pragma unroll
        for (int r = 0; r < NREP; ++r) s += S[((size_t)r << 15) + (b << 6) + t];
        sp[t] = s;
    }
    __syncthreads();
    float acc = 0.f;
#pragma unroll
    for (int o = 0; o < 64; ++o) acc = fmaf(sp[o], Wout[o * 128 + t], acc);
    out[b * 128 + t] = 0.125f * acc;
}

extern "C" void kernel_launch(void* const* d_in, const int* in_sizes, int n_in,
                              void* d_out, int out_size, void* d_ws, size_t ws_size,
                              hipStream_t stream)
{
    const float* x    = (const float*)d_in[0];
    const int*   bidx = (const int*)d_in[1];
    const float* W0   = (const float*)d_in[3];   // W0_0 (64,256)
    const float* W1   = (const float*)d_in[7];   // W1_0 (64,256)
    const float* Wout = (const float*)d_in[11];  // W_out (64,128)
    float* S   = (float*)d_ws;                    // NREP replicas of 512x64
    float* out = (float*)d_out;

    hipMemsetAsync(S, 0, (size_t)NREP * 32768 * sizeof(float), stream);
    hipLaunchKernelGGL(phase1, dim3(512), dim3(256), 0, stream, x, bidx, W0, W1, S);
    hipLaunchKernelGGL(phase2, dim3(512), dim3(128), 0, stream, S, Wout, out);
}

// Round 8
// 46.371 us; speedup vs baseline: 1.9968x; 1.2746x over previous
//
#include <hip/hip_runtime.h>
#include <hip/hip_bf16.h>

#define CSTF 1.676543f
#define NREP 16

typedef __bf16 bf16x8 __attribute__((ext_vector_type(8)));
typedef float  f32x4  __attribute__((ext_vector_type(4)));

__device__ __forceinline__ float silu_n(float y) {
    return CSTF * y * __builtin_amdgcn_rcpf(1.0f + __expf(-y));
}

struct XG { f32x4 a, b, c, d; };

__device__ __forceinline__ XG loadx(const float* p) {
    XG r;
    r.a = *(const f32x4*)(p);
    r.b = *(const f32x4*)(p + 4);
    r.c = *(const f32x4*)(p + 32);
    r.d = *(const f32x4*)(p + 36);
    return r;
}

// One 16-atom group; vb = this lane's 4 batch indices (atoms 4g+0..3 of group).
#define PROC16(cur, vb) { \
  bf16x8 a0, a1; \
  _Pragma("unroll") \
  for (int j = 0; j < 4; ++j) { \
    a0[j] = (__bf16)cur.a[j]; a0[j+4] = (__bf16)cur.b[j]; \
    a1[j] = (__bf16)cur.c[j]; a1[j+4] = (__bf16)cur.d[j]; \
  } \
  const f32x4 zf = {0.f, 0.f, 0.f, 0.f}; \
  _Pragma("unroll") \
  for (int nt = 0; nt < 4; ++nt) { \
    f32x4 acc = __builtin_amdgcn_mfma_f32_16x16x32_bf16(a0, wf0[0][nt], zf, 0, 0, 0); \
    acc = __builtin_amdgcn_mfma_f32_16x16x32_bf16(a1, wf0[1][nt], acc, 0, 0, 0); \
    _Pragma("unroll") \
    for (int r = 0; r < 4; ++r) \
      sb[w][4*g + r][nt*16 + c] = __float2bfloat16(silu_n(acc[r])); \
  } \
  const bf16x8 sa0 = *(const bf16x8*)&sb[w][c][g*8]; \
  const bf16x8 sa1 = *(const bf16x8*)&sb[w][c][g*8 + 32]; \
  _Pragma("unroll") \
  for (int nt = 0; nt < 4; ++nt) { \
    f32x4 z = __builtin_amdgcn_mfma_f32_16x16x32_bf16(sa0, wf1[0][nt], zf, 0, 0, 0); \
    z = __builtin_amdgcn_mfma_f32_16x16x32_bf16(sa1, wf1[1][nt], z, 0, 0, 0); \
    atomicAdd(&Srep[(vb.x << 6) + nt*16 + c], silu_n(z[0])); \
    atomicAdd(&Srep[(vb.y << 6) + nt*16 + c], silu_n(z[1])); \
    atomicAdd(&Srep[(vb.z << 6) + nt*16 + c], silu_n(z[2])); \
    atomicAdd(&Srep[(vb.w << 6) + nt*16 + c], silu_n(z[3])); \
  } \
}

// Phase 1: s2 = silu(silu(x@W0*.125)@W1*.125) via bf16 MFMA, atomics into
// NREP replicated S[512][64] tables. 512 blocks x 4 waves x 64 atoms,
// 2-group-deep x prefetch.
__global__ __launch_bounds__(256, 3) void phase1(
    const float* __restrict__ x, const int* __restrict__ bidx,
    const float* __restrict__ W0, const float* __restrict__ W1,
    float* __restrict__ S)
{
    __shared__ __align__(16) __hip_bfloat16 sb[4][16][72];
    const int tid  = threadIdx.x;
    const int lane = tid & 63;
    const int w    = tid >> 6;
    const int c    = lane & 15;
    const int g    = lane >> 4;

    const int wbase = (blockIdx.x * 4 + w) * 64;   // 64 atoms per wave
    const float* px = x + (size_t)(wbase + c) * 1024 + g * 8;

    // issue first TWO groups' loads before anything else (deep pipeline)
    XG   c0 = loadx(px);
    XG   c1 = loadx(px + 16 * 1024);
    int4 b0 = *(const int4*)&bidx[wbase + 4 * g];
    int4 b1 = *(const int4*)&bidx[wbase + 16 + 4 * g];

    // W0/W1 as B-fragments, 1/sqrt(64) folded into bf16 weights (L2-hot)
    bf16x8 wf0[2][4], wf1[2][4];
#pragma unroll
    for (int ks = 0; ks < 2; ++ks)
#pragma unroll
        for (int nt = 0; nt < 4; ++nt) {
            bf16x8 f0, f1;
#pragma unroll
            for (int j = 0; j < 8; ++j) {
                const int k = ks * 32 + g * 8 + j;
                f0[j] = (__bf16)(0.125f * W0[k * 256 + nt * 16 + c]);
                f1[j] = (__bf16)(0.125f * W1[k * 256 + nt * 16 + c]);
            }
            wf0[ks][nt] = f0;
            wf1[ks][nt] = f1;
        }

    float* Srep = S + ((size_t)(blockIdx.x & (NREP - 1)) << 15);

#pragma unroll 1
    for (int gi = 0; gi < 4; ++gi) {
        XG   nc = c1;
        int4 nb = b1;
        if (gi < 2) {   // keep pipeline 2 deep
            c1 = loadx(px + (size_t)(gi + 2) * 16 * 1024);
            b1 = *(const int4*)&bidx[wbase + (gi + 2) * 16 + 4 * g];
        }
        PROC16(c0, b0);
        c0 = nc;
        b0 = nb;
    }
}

// out[b, t] = 0.125 * sum_o (sum_r S_r[b,o]) * Wout[o, t]
__global__ __launch_bounds__(128) void phase2(
    const float* __restrict__ S, const float* __restrict__ Wout,
    float* __restrict__ out)
{
    __shared__ float sp[64];
    const int b = blockIdx.x, t = threadIdx.x;
    if (t < 64) {
        float s = 0.f;
#pragma unroll
        for (int r = 0; r < NREP; ++r) s += S[((size_t)r << 15) + (b << 6) + t];
        sp[t] = s;
    }
    __syncthreads();
    float acc = 0.f;
#pragma unroll
    for (int o = 0; o < 64; ++o) acc = fmaf(sp[o], Wout[o * 128 + t], acc);
    out[b * 128 + t] = 0.125f * acc;
}

extern "C" void kernel_launch(void* const* d_in, const int* in_sizes, int n_in,
                              void* d_out, int out_size, void* d_ws, size_t ws_size,
                              hipStream_t stream)
{
    const float* x    = (const float*)d_in[0];
    const int*   bidx = (const int*)d_in[1];
    const float* W0   = (const float*)d_in[3];   // W0_0 (64,256)
    const float* W1   = (const float*)d_in[7];   // W1_0 (64,256)
    const float* Wout = (const float*)d_in[11];  // W_out (64,128)
    float* S   = (float*)d_ws;                    // NREP replicas of 512x64
    float* out = (float*)d_out;

    hipMemsetAsync(S, 0, (size_t)NREP * 32768 * sizeof(float), stream);
    hipLaunchKernelGGL(phase1, dim3(512), dim3(256), 0, stream, x, bidx, W0, W1, S);
    hipLaunchKernelGGL(phase2, dim3(512), dim3(128), 0, stream, S, Wout, out);
}